// Round 6
// baseline (137.329 us; speedup 1.0000x reference)
//
#include <hip/hip_runtime.h>

// ---------------------------------------------------------------------------
// ModernBertAttention: x[4,2048,768] -> QKV gemm(+RoPE) -> sliding-window
// MFMA attention (window=64) -> out-proj gemm.  out f32 [4,2048,768].
// ---------------------------------------------------------------------------

typedef __attribute__((ext_vector_type(8))) _Float16 f16x8;
typedef __attribute__((ext_vector_type(4))) float    f32x4;

#define BDIM 4
#define SDIM 2048
#define HDIM 768
#define NH   12
#define HD   64
#define NQKV 2304   // 3*HDIM
#define MROWS 8192  // B*S

// ---------------------------------------------------------------------------
__device__ __forceinline__ void gload16(const void* g, void* l) {
    __builtin_amdgcn_global_load_lds(
        (__attribute__((address_space(1))) void*)(g),
        (__attribute__((address_space(3))) void*)(l),
        16, 0, 0);
}

// --------------------------- f32 -> f16 convert ----------------------------
__global__ __launch_bounds__(256) void cvt_f32_f16(
    const float* __restrict__ src, _Float16* __restrict__ dst, int n8)
{
    int i = blockIdx.x * 256 + threadIdx.x;
    if (i >= n8) return;
    const float4* s4 = (const float4*)src + (long)i * 2;
    float4 a = s4[0], b = s4[1];
    f16x8 o;
    o[0] = (_Float16)a.x; o[1] = (_Float16)a.y;
    o[2] = (_Float16)a.z; o[3] = (_Float16)a.w;
    o[4] = (_Float16)b.x; o[5] = (_Float16)b.y;
    o[6] = (_Float16)b.z; o[7] = (_Float16)b.w;
    *((f16x8*)dst + i) = o;
}

// ------------------------------- GEMM --------------------------------------
// C[M,N] = A[M,K] * Bt[N,K]^T, fp16 inputs, fp32 accum.
// 256 x BN tile (BN = NF*64), BK=32, 8 waves (512 thr), double-buffered LDS
// (64/48 KB -> 2 blocks/CU), counted-vmcnt pipeline (round-5 schedule).
// Wave grid 2x4: wave w covers rows [wr*128, +128), cols [wc*NF*16, +NF*16).
// Raised arithmetic intensity: per k-step a block moves (256+BN)*32*2B for
// 2*256*BN*32 FLOP -> ~2x less L2 panel traffic than the 128^2 tile.
// EPI==0: plain f32 C store.
// EPI==1 (requires NF==4): RoPE on q/k, scatter q/k/v (f16) to [B,nh,S,hd].
template <int NF, int EPI>
__global__ __launch_bounds__(512) void gemm_kernel(
    const _Float16* __restrict__ A,
    const _Float16* __restrict__ Bt,
    float* __restrict__ C,
    const float* __restrict__ cosp,
    const float* __restrict__ sinp,
    _Float16* __restrict__ qh,
    _Float16* __restrict__ kh,
    _Float16* __restrict__ vh,
    int M, int N, int K)
{
    constexpr int BN = NF * 64;
    __shared__ __align__(16) _Float16 lsA[2][256 * 32];
    __shared__ __align__(16) _Float16 lsB[2][BN * 32];

    int nTn = N / BN;
    int nwg = gridDim.x;
    int bid = blockIdx.x;
    int cpx = nwg >> 3;                       // both grids are %8 == 0
    int wg  = (bid & 7) * cpx + (bid >> 3);   // XCD-aware bijective swizzle
    int tm = wg / nTn, tn = wg % nTn;
    int m0 = tm << 8, n0 = tn * BN;

    int tid  = threadIdx.x;
    int lane = tid & 63;
    int w    = tid >> 6;
    int wr   = w >> 2, wc = w & 3;
    int l15  = lane & 15, lk = lane >> 4;

    f32x4 acc[8][NF] = {};

    // staging: thread covers rows {w*16 + lane/4, +128}, col granule lane&3.
    // LDS dest is wave-linear: byte (k*8+w)*1024 + lane*16.
    int rstage = w * 16 + (lane >> 2);        // 0..127
    int cstage = (lane & 3) << 3;
    const _Float16* gaT = A  + (long)(m0 + rstage) * K + cstage;
    const _Float16* gbT = Bt + (long)(n0 + rstage) * K + cstage;
    const long gstep = (long)128 * K;
    _Float16* la0 = &lsA[0][rstage * 32 + cstage];
    _Float16* la1 = &lsA[1][rstage * 32 + cstage];
    _Float16* lb0 = &lsB[0][rstage * 32 + cstage];
    _Float16* lb1 = &lsB[1][rstage * 32 + cstage];

    auto STAGE = [&](_Float16* la, _Float16* lb, int t) {
        const _Float16* ga_ = gaT + (long)t * 32;
        const _Float16* gb_ = gbT + (long)t * 32;
        gload16(ga_,         la);
        gload16(ga_ + gstep, la + 4096);
        gload16(gb_,         lb);
        if constexpr (NF == 4) gload16(gb_ + gstep, lb + 4096);
    };
    auto WAIT_PIPE = [] {   // in-flight after STAGE = 2 stages; wait for older one
        if constexpr (NF == 4) asm volatile("s_waitcnt vmcnt(4)" ::: "memory");
        else                   asm volatile("s_waitcnt vmcnt(3)" ::: "memory");
    };

    const int NK = K >> 5;   // 24

    // prologue: 2 tiles in flight
    STAGE(la0, lb0, 0);
    STAGE(la1, lb1, 1);
    WAIT_PIPE();                               // tile 0 resident
    __builtin_amdgcn_s_barrier();

    int cur = 0;
    for (int it = 0; it < NK; ++it) {
        const _Float16* lsAc = lsA[cur];
        const _Float16* lsBc = lsB[cur];
        f16x8 af[8], bfr[NF];
#pragma unroll
        for (int mf = 0; mf < 8; ++mf)
            af[mf] = *(const f16x8*)&lsAc[(wr * 128 + mf * 16 + l15) * 32 + lk * 8];
#pragma unroll
        for (int nf = 0; nf < NF; ++nf)
            bfr[nf] = *(const f16x8*)&lsBc[(wc * (NF * 16) + nf * 16 + l15) * 32 + lk * 8];

        asm volatile("s_waitcnt lgkmcnt(0)" ::: "memory");  // my reads landed
        __builtin_amdgcn_s_barrier();                       // all waves done with buf[cur]

        if (it + 2 < NK)
            STAGE(cur ? la1 : la0, cur ? lb1 : lb0, it + 2);

#pragma unroll
        for (int mf = 0; mf < 8; ++mf)
#pragma unroll
            for (int nf = 0; nf < NF; ++nf)
                acc[mf][nf] = __builtin_amdgcn_mfma_f32_16x16x32_f16(
                    af[mf], bfr[nf], acc[mf][nf], 0, 0, 0);

        if (it + 1 < NK) {
            if (it + 2 < NK) WAIT_PIPE();      // tile it+1 resident, it+2 in flight
            else asm volatile("s_waitcnt vmcnt(0)" ::: "memory");
            __builtin_amdgcn_s_barrier();
        }
        cur ^= 1;
    }

    if constexpr (EPI == 0) {
#pragma unroll
        for (int mf = 0; mf < 8; ++mf)
#pragma unroll
            for (int nf = 0; nf < NF; ++nf)
#pragma unroll
                for (int j = 0; j < 4; ++j) {
                    int gr = m0 + wr * 128 + mf * 16 + lk * 4 + j;
                    int gc = n0 + wc * (NF * 16) + nf * 16 + l15;
                    C[(long)gr * N + gc] = acc[mf][nf][j];
                }
    } else {
        int ht = (n0 >> 6) + wc;       // [0,36): t*12 + h  (one chunk per wave)
        int t  = ht / NH;
        int h  = ht - t * NH;
        int b  = m0 >> 11;             // 256-row tile never straddles a batch
        long base_bh = ((long)(b * NH + h)) * SDIM;
#pragma unroll
        for (int mf = 0; mf < 8; ++mf) {
#pragma unroll
            for (int j = 0; j < 4; ++j) {
                int gr = m0 + wr * 128 + mf * 16 + lk * 4 + j;
                int s  = gr & (SDIM - 1);
                if (t == 2) {
#pragma unroll
                    for (int nf = 0; nf < NF; ++nf) {
                        int d = nf * 16 + l15;
                        vh[(base_bh + s) * HD + d] = (_Float16)acc[mf][nf][j];
                    }
                } else {
                    float vals[4];
#pragma unroll
                    for (int nf = 0; nf < 4; ++nf) vals[nf] = acc[mf][nf % NF][j];
#pragma unroll
                    for (int nf = 0; nf < 4; ++nf) {
                        int d = nf * 16 + l15;
                        float cc = cosp[(long)gr * HD + d];
                        float ss = sinp[(long)gr * HD + d];
                        float pv = (nf < 2) ? -vals[nf + 2] : vals[nf - 2];
                        float o  = vals[nf] * cc + pv * ss;
                        long oidx = (base_bh + s) * HD + d;
                        if (t == 0) qh[oidx] = (_Float16)o;
                        else        kh[oidx] = (_Float16)o;
                    }
                }
            }
        }
    }
}

// ---------------------------- MFMA attention --------------------------------
// Block = 4 waves = one (b,h, 64-query tile); key window = 192 keys.
// QK^T: A=Q (direct global frags), B=K rows (direct global frags).
// exp+mask in-register; row-sums via 16-lane shfl_xor; P -> LDS f16.
// V staged once per block to LDS transposed f16; PV MFMA from LDS.
#define SSTR 200   // lsVT row stride (f16): 400B, 16B-aligned, conflict-benign
#define PSTR 200   // lsP  row stride (f16)
__global__ __launch_bounds__(256) void attn_mfma(
    const _Float16* __restrict__ qh,
    const _Float16* __restrict__ kh,
    const _Float16* __restrict__ vh,
    _Float16* __restrict__ yh)
{
    __shared__ __align__(16) _Float16 lsVT[64 * SSTR];
    __shared__ __align__(16) _Float16 lsP [64 * PSTR];

    int bid = blockIdx.x;
    int qt  = bid & 31;
    int bh  = bid >> 5;
    int q0  = qt << 6;
    int k0  = q0 - 64;
    int tid = threadIdx.x;
    int lane = tid & 63;
    int w = tid >> 6;
    int l15 = lane & 15, lg = lane >> 4;

    const _Float16* Qb = qh + (long)bh * SDIM * HD;
    const _Float16* Kb = kh + (long)bh * SDIM * HD;
    const _Float16* Vb = vh + (long)bh * SDIM * HD;

    // ---- stage V^T into LDS: wave w covers d in [w*16, w*16+16) ----
#pragma unroll
    for (int c = 0; c < 3; ++c) {
        int rk = c * 64 + lane;
        int s  = k0 + rk;
        s = s < 0 ? 0 : (s >= SDIM ? SDIM - 1 : s);
        const f16x8* vr = (const f16x8*)(Vb + (long)s * HD + w * 16);
        f16x8 v0 = vr[0], v1 = vr[1];
#pragma unroll
        for (int e = 0; e < 8; ++e) {
            lsVT[(w * 16 + e)     * SSTR + rk] = v0[e];
            lsVT[(w * 16 + 8 + e) * SSTR + rk] = v1[e];
        }
    }

    // ---- Q fragments (A-operand: row=l15, k=lg*8+e) ----
    int qrow = q0 + w * 16 + l15;
    const f16x8* qp = (const f16x8*)(Qb + (long)qrow * HD + lg * 8);
    f16x8 qa0 = qp[0];
    f16x8 qa1 = qp[4];   // +32 f16

    // ---- QK^T, mask, exp, P->LDS ----
    float sums[4] = {0.f, 0.f, 0.f, 0.f};
    int iqb = w * 16 + lg * 4;   // query offset (from q0) of this lane's D rows
#pragma unroll 4
    for (int kt = 0; kt < 12; ++kt) {
        int krow = k0 + kt * 16 + l15;
        int kcl = krow < 0 ? 0 : (krow >= SDIM ? SDIM - 1 : krow);
        const f16x8* kp = (const f16x8*)(Kb + (long)kcl * HD + lg * 8);
        f16x8 kb0 = kp[0], kb1 = kp[4];
        f32x4 acc = {0.f, 0.f, 0.f, 0.f};
        acc = __builtin_amdgcn_mfma_f32_16x16x32_f16(qa0, kb0, acc, 0, 0, 0);
        acc = __builtin_amdgcn_mfma_f32_16x16x32_f16(qa1, kb1, acc, 0, 0, 0);
        int jk = kt * 16 + l15;              // key offset (from k0) of D col
        bool kin = (krow >= 0) && (krow < SDIM);
#pragma unroll
        for (int j = 0; j < 4; ++j) {
            int i = iqb + j;
            bool valid = kin && (jk >= i) && (jk <= i + 128);
            float p = valid ? __expf(acc[j] * 0.125f) : 0.f;
            sums[j] += p;
            lsP[(w * 16 + lg * 4 + j) * PSTR + jk] = (_Float16)p;
        }
    }

    // ---- row-sums: reduce across the 16 lanes of each lg group ----
#pragma unroll
    for (int m = 1; m < 16; m <<= 1) {
#pragma unroll
        for (int j = 0; j < 4; ++j)
            sums[j] += __shfl_xor(sums[j], m, 64);
    }
    float inv[4];
#pragma unroll
    for (int j = 0; j < 4; ++j) inv[j] = 1.f / sums[j];

    __syncthreads();   // lsVT staged (cross-wave); lsP is intra-wave

    // ---- PV: A=P[q=l15, k=lg*8+e], B=V^T -> lane B[k, d=l15] ----
    f32x4 accy[4] = {};
    const _Float16* prow = &lsP[(w * 16 + l15) * PSTR + lg * 8];
#pragma unroll
    for (int kc = 0; kc < 6; ++kc) {
        f16x8 pa = *(const f16x8*)(prow + kc * 32);
#pragma unroll
        for (int dt = 0; dt < 4; ++dt) {
            f16x8 vb = *(const f16x8*)&lsVT[(dt * 16 + l15) * SSTR + kc * 32 + lg * 8];
            accy[dt] = __builtin_amdgcn_mfma_f32_16x16x32_f16(pa, vb, accy[dt], 0, 0, 0);
        }
    }

    // ---- epilogue: y*inv -> yh[b, s, h*64+d] f16 ----
    int b = bh / NH, h = bh - (bh / NH) * NH;
    long outbase = ((long)b * SDIM) * HDIM + (long)h * HD;
#pragma unroll
    for (int dt = 0; dt < 4; ++dt) {
#pragma unroll
        for (int j = 0; j < 4; ++j) {
            int srow = q0 + w * 16 + lg * 4 + j;
            yh[outbase + (long)srow * HDIM + dt * 16 + l15] =
                (_Float16)(accy[dt][j] * inv[j]);
        }
    }
}

// ---------------------------------------------------------------------------
extern "C" void kernel_launch(void* const* d_in, const int* in_sizes, int n_in,
                              void* d_out, int out_size, void* d_ws, size_t ws_size,
                              hipStream_t stream)
{
    const float* x    = (const float*)d_in[0];
    const float* cosp = (const float*)d_in[1];
    const float* sinp = (const float*)d_in[2];
    const float* Wqkv = (const float*)d_in[3];
    const float* Wo   = (const float*)d_in[4];
    float* out = (float*)d_out;

    char* ws = (char*)d_ws;
    _Float16* xh    = (_Float16*)(ws);                    // 12,582,912
    _Float16* wqkvh = (_Float16*)(ws + 12582912);         //  3,538,944
    _Float16* woh   = (_Float16*)(ws + 16121856);         //  1,179,648
    _Float16* qh    = (_Float16*)(ws + 17301504);         // 12,582,912
    _Float16* kh    = (_Float16*)(ws + 29884416);         // 12,582,912
    _Float16* vh    = (_Float16*)(ws + 42467328);         // 12,582,912
    _Float16* yh    = (_Float16*)(ws + 55050240);         // 12,582,912 -> 67,633,152 total

    // 1) convert inputs to fp16
    cvt_f32_f16<<<(MROWS * HDIM / 8 + 255) / 256, 256, 0, stream>>>(x, xh, MROWS * HDIM / 8);
    cvt_f32_f16<<<(NQKV * HDIM / 8 + 255) / 256, 256, 0, stream>>>(Wqkv, wqkvh, NQKV * HDIM / 8);
    cvt_f32_f16<<<(HDIM * HDIM / 8 + 255) / 256, 256, 0, stream>>>(Wo, woh, HDIM * HDIM / 8);

    // 2) QKV gemm with fused RoPE + scatter epilogue (256x256 tile)
    {
        dim3 grid((MROWS / 256) * (NQKV / 256));   // 32*9 = 288
        gemm_kernel<4, 1><<<grid, 512, 0, stream>>>(
            xh, wqkvh, nullptr, cosp, sinp, qh, kh, vh, MROWS, NQKV, HDIM);
    }

    // 3) sliding-window MFMA attention
    {
        dim3 grid(BDIM * NH * (SDIM / 64));        // 1536
        attn_mfma<<<grid, 256, 0, stream>>>(qh, kh, vh, yh);
    }

    // 4) output projection (256x128 tile)
    {
        dim3 grid((MROWS / 256) * (HDIM / 128));   // 32*6 = 192
        gemm_kernel<2, 0><<<grid, 512, 0, stream>>>(
            yh, woh, out, nullptr, nullptr, nullptr, nullptr, nullptr,
            MROWS, HDIM, HDIM);
    }
}

// Round 7
// 125.605 us; speedup vs baseline: 1.0933x; 1.0933x over previous
//
#include <hip/hip_runtime.h>

// ---------------------------------------------------------------------------
// ModernBertAttention: x[4,2048,768] -> QKV gemm(+RoPE) -> sliding-window
// MFMA attention (window=64) -> out-proj gemm.  out f32 [4,2048,768].
// ---------------------------------------------------------------------------

typedef __attribute__((ext_vector_type(8))) _Float16 f16x8;
typedef __attribute__((ext_vector_type(4))) float    f32x4;

#define BDIM 4
#define SDIM 2048
#define HDIM 768
#define NH   12
#define HD   64
#define NQKV 2304   // 3*HDIM
#define MROWS 8192  // B*S

// ---------------------------------------------------------------------------
__device__ __forceinline__ void gload16(const void* g, void* l) {
    __builtin_amdgcn_global_load_lds(
        (__attribute__((address_space(1))) void*)(g),
        (__attribute__((address_space(3))) void*)(l),
        16, 0, 0);
}

// --------------------------- f32 -> f16 convert ----------------------------
__global__ __launch_bounds__(256) void cvt_f32_f16(
    const float* __restrict__ src, _Float16* __restrict__ dst, int n8)
{
    int i = blockIdx.x * 256 + threadIdx.x;
    if (i >= n8) return;
    const float4* s4 = (const float4*)src + (long)i * 2;
    float4 a = s4[0], b = s4[1];
    f16x8 o;
    o[0] = (_Float16)a.x; o[1] = (_Float16)a.y;
    o[2] = (_Float16)a.z; o[3] = (_Float16)a.w;
    o[4] = (_Float16)b.x; o[5] = (_Float16)b.y;
    o[6] = (_Float16)b.z; o[7] = (_Float16)b.w;
    *((f16x8*)dst + i) = o;
}

// ---------------------- 4-phase pipelined GEMM ------------------------------
// C[M,N] = A[M,K]*Bt[N,K]^T, fp16 in, fp32 acc. BM=128, BN=WN*64, BK=64.
// 2*WN waves (wave tile 64x64). K-tile = 4 phases, each:
//   {ds_read frag subtile ; issue stage loads} -> s_barrier -> lgkmcnt(0)
//   -> setprio(1) 8x MFMA setprio(0) -> s_barrier
// vmcnt(0) once per K-tile boundary (loads issued >=2 phases earlier).
// LDS XOR-swizzle both-sides (rule 21): phys_granule = log_granule ^ (row&7);
// global_load_lds dest stays linear, SOURCE column pre-swizzled; ds_read
// applies the same XOR -> conflict-free b128 reads at 128B row stride.
// EPI==0: f32 C store. EPI==1 (WN==4): RoPE q/k + scatter q/k/v f16 [B,nh,S,hd].
template <int WN, int EPI>
__global__ __launch_bounds__(WN * 128) void gemm_kernel(
    const _Float16* __restrict__ A,
    const _Float16* __restrict__ Bt,
    float* __restrict__ C,
    const float* __restrict__ cosp,
    const float* __restrict__ sinp,
    _Float16* __restrict__ qh,
    _Float16* __restrict__ kh,
    _Float16* __restrict__ vh,
    int M, int N, int K)
{
    constexpr int BN = WN * 64;
    constexpr int T  = WN * 128;   // threads
    constexpr int AL = 8 / WN;     // A stage loads/thread (16KB/(T*16B))
    __shared__ __align__(16) _Float16 lsA[2][128 * 64];
    __shared__ __align__(16) _Float16 lsB[2][BN * 64];

    int nTn = N / BN;
    int nwg = gridDim.x;
    int bid = blockIdx.x;
    int cpx = nwg >> 3;                       // grids are %8==0
    int wg  = (bid & 7) * cpx + (bid >> 3);   // XCD-aware bijective swizzle
    int tm = wg / nTn, tn = wg % nTn;
    int m0 = tm << 7, n0 = tn * BN;

    int tid  = threadIdx.x;
    int lane = tid & 63;
    int w    = tid >> 6;
    int wr   = w / WN, wc = w % WN;           // wave grid 2 x WN
    int l15  = lane & 15, lk = lane >> 4;

    f32x4 acc[4][4] = {};

    // ---- staging addressing (pre-swizzled source, linear LDS dest) ----
    // thread covers row (tid>>3)+i*(T/8), phys granule tid&7;
    // source logical granule = (tid&7) ^ (row&7), row&7 == (tid>>3)&7.
    int gsrc = (tid & 7) ^ ((tid >> 3) & 7);
    const _Float16* gA = A  + (long)(m0 + (tid >> 3)) * K + gsrc * 8;
    const _Float16* gB = Bt + (long)(n0 + (tid >> 3)) * K + gsrc * 8;
    const long rstep = (long)(T >> 3) * K;    // (T/8) rows per load group
    int dst = tid * 8;                        // f16: (tid>>3)*64 + (tid&7)*8

    auto STAGE_A = [&](int buf, int t) {
#pragma unroll
        for (int i = 0; i < AL; ++i)
            gload16(gA + i * rstep + t * 64, &lsA[buf][dst + i * (T >> 3) * 64]);
    };
    auto STAGE_B = [&](int buf, int t, int j0) {   // 2 of the 4 B loads
#pragma unroll
        for (int j = 0; j < 2; ++j)
            gload16(gB + (j0 + j) * rstep + t * 64,
                    &lsB[buf][dst + (j0 + j) * (T >> 3) * 64]);
    };

    // frag read: row r, ksub s, granule (s*4+lk) ^ (r&7); r&7 == l15&7
    int xg = l15 & 7;
    auto RD_A = [&](const _Float16* base, int s, f16x8* af) {
#pragma unroll
        for (int mf = 0; mf < 4; ++mf) {
            int row = wr * 64 + mf * 16 + l15;
            af[mf] = *(const f16x8*)&base[row * 64 + ((((s << 2) | lk) ^ xg) << 3)];
        }
    };
    auto RD_B2 = [&](const _Float16* base, int s, int nh, f16x8* bf) {
#pragma unroll
        for (int n2 = 0; n2 < 2; ++n2) {
            int row = wc * 64 + (nh * 2 + n2) * 16 + l15;
            bf[n2] = *(const f16x8*)&base[row * 64 + ((((s << 2) | lk) ^ xg) << 3)];
        }
    };

#define PHASE_SYNC()                                            \
    __builtin_amdgcn_s_barrier();                               \
    asm volatile("s_waitcnt lgkmcnt(0)" ::: "memory");          \
    __builtin_amdgcn_sched_barrier(0);

#define MM8(af, bf, nh)                                         \
    __builtin_amdgcn_s_setprio(1);                              \
    _Pragma("unroll")                                           \
    for (int mf = 0; mf < 4; ++mf) {                            \
        acc[mf][(nh)*2+0] = __builtin_amdgcn_mfma_f32_16x16x32_f16( \
            af[mf], bf[0], acc[mf][(nh)*2+0], 0, 0, 0);          \
        acc[mf][(nh)*2+1] = __builtin_amdgcn_mfma_f32_16x16x32_f16( \
            af[mf], bf[1], acc[mf][(nh)*2+1], 0, 0, 0);          \
    }                                                           \
    __builtin_amdgcn_s_setprio(0);                              \
    __builtin_amdgcn_s_barrier();

    const int NT = K >> 6;   // 12 K-tiles of BK=64

    // prologue: stage tile 0 into buf 0
    STAGE_A(0, 0);
    STAGE_B(0, 0, 0);
    STAGE_B(0, 0, 2);
    asm volatile("s_waitcnt vmcnt(0)" ::: "memory");
    __builtin_amdgcn_s_barrier();

    int cur = 0;
    for (int t = 0; t < NT; ++t) {
        const _Float16* a_cur = lsA[cur];
        const _Float16* b_cur = lsB[cur];
        int nxt = cur ^ 1;
        bool more = (t + 1 < NT);
        f16x8 af[4], bf[2];

        // phase 0: A frags s=0, B nf01 s=0; stage A(t+1)
        RD_A(a_cur, 0, af);
        RD_B2(b_cur, 0, 0, bf);
        if (more) STAGE_A(nxt, t + 1);
        PHASE_SYNC();
        MM8(af, bf, 0);

        // phase 1: B nf23 s=0; stage B(t+1) half 1
        RD_B2(b_cur, 0, 1, bf);
        if (more) STAGE_B(nxt, t + 1, 0);
        PHASE_SYNC();
        MM8(af, bf, 1);

        // phase 2: A frags s=1, B nf01 s=1; stage B(t+1) half 2
        RD_A(a_cur, 1, af);
        RD_B2(b_cur, 1, 0, bf);
        if (more) STAGE_B(nxt, t + 1, 2);
        PHASE_SYNC();
        MM8(af, bf, 0);

        // phase 3: B nf23 s=1; no staging
        RD_B2(b_cur, 1, 1, bf);
        PHASE_SYNC();
        __builtin_amdgcn_s_setprio(1);
#pragma unroll
        for (int mf = 0; mf < 4; ++mf) {
            acc[mf][2] = __builtin_amdgcn_mfma_f32_16x16x32_f16(af[mf], bf[0], acc[mf][2], 0, 0, 0);
            acc[mf][3] = __builtin_amdgcn_mfma_f32_16x16x32_f16(af[mf], bf[1], acc[mf][3], 0, 0, 0);
        }
        __builtin_amdgcn_s_setprio(0);

        // K-tile boundary: next tile must be resident before phase 0 reads it
        if (more) asm volatile("s_waitcnt vmcnt(0)" ::: "memory");
        __builtin_amdgcn_s_barrier();
        cur = nxt;
    }
#undef PHASE_SYNC
#undef MM8

    if constexpr (EPI == 0) {
#pragma unroll
        for (int mf = 0; mf < 4; ++mf)
#pragma unroll
            for (int nf = 0; nf < 4; ++nf)
#pragma unroll
                for (int j = 0; j < 4; ++j) {
                    int gr = m0 + wr * 64 + mf * 16 + lk * 4 + j;
                    int gc = n0 + wc * 64 + nf * 16 + l15;
                    C[(long)gr * N + gc] = acc[mf][nf][j];
                }
    } else {
        int ht = (n0 >> 6) + wc;       // [0,36): t*12 + h
        int tq = ht / NH;
        int h  = ht - tq * NH;
        int b  = m0 >> 11;             // 128-row tile never straddles a batch
        long base_bh = ((long)(b * NH + h)) * SDIM;
#pragma unroll
        for (int mf = 0; mf < 4; ++mf) {
#pragma unroll
            for (int j = 0; j < 4; ++j) {
                int gr = m0 + wr * 64 + mf * 16 + lk * 4 + j;
                int s  = gr & (SDIM - 1);
                if (tq == 2) {
#pragma unroll
                    for (int nf = 0; nf < 4; ++nf) {
                        int d = nf * 16 + l15;
                        vh[(base_bh + s) * HD + d] = (_Float16)acc[mf][nf][j];
                    }
                } else {
                    float vals[4];
#pragma unroll
                    for (int nf = 0; nf < 4; ++nf) vals[nf] = acc[mf][nf][j];
#pragma unroll
                    for (int nf = 0; nf < 4; ++nf) {
                        int d = nf * 16 + l15;
                        float cc = cosp[(long)gr * HD + d];
                        float ss = sinp[(long)gr * HD + d];
                        float pv = (nf < 2) ? -vals[nf + 2] : vals[nf - 2];
                        float o  = vals[nf] * cc + pv * ss;
                        long oidx = (base_bh + s) * HD + d;
                        if (tq == 0) qh[oidx] = (_Float16)o;
                        else         kh[oidx] = (_Float16)o;
                    }
                }
            }
        }
    }
}

// ---------------------------- MFMA attention --------------------------------
// Block = 4 waves = one (b,h, 64-query tile); key window = 192 keys.
#define SSTR 200
#define PSTR 200
__global__ __launch_bounds__(256) void attn_mfma(
    const _Float16* __restrict__ qh,
    const _Float16* __restrict__ kh,
    const _Float16* __restrict__ vh,
    _Float16* __restrict__ yh)
{
    __shared__ __align__(16) _Float16 lsVT[64 * SSTR];
    __shared__ __align__(16) _Float16 lsP [64 * PSTR];

    int bid = blockIdx.x;
    int qt  = bid & 31;
    int bh  = bid >> 5;
    int q0  = qt << 6;
    int k0  = q0 - 64;
    int tid = threadIdx.x;
    int lane = tid & 63;
    int w = tid >> 6;
    int l15 = lane & 15, lg = lane >> 4;

    const _Float16* Qb = qh + (long)bh * SDIM * HD;
    const _Float16* Kb = kh + (long)bh * SDIM * HD;
    const _Float16* Vb = vh + (long)bh * SDIM * HD;

#pragma unroll
    for (int c = 0; c < 3; ++c) {
        int rk = c * 64 + lane;
        int s  = k0 + rk;
        s = s < 0 ? 0 : (s >= SDIM ? SDIM - 1 : s);
        const f16x8* vr = (const f16x8*)(Vb + (long)s * HD + w * 16);
        f16x8 v0 = vr[0], v1 = vr[1];
#pragma unroll
        for (int e = 0; e < 8; ++e) {
            lsVT[(w * 16 + e)     * SSTR + rk] = v0[e];
            lsVT[(w * 16 + 8 + e) * SSTR + rk] = v1[e];
        }
    }

    int qrow = q0 + w * 16 + l15;
    const f16x8* qp = (const f16x8*)(Qb + (long)qrow * HD + lg * 8);
    f16x8 qa0 = qp[0];
    f16x8 qa1 = qp[4];

    float sums[4] = {0.f, 0.f, 0.f, 0.f};
    int iqb = w * 16 + lg * 4;
#pragma unroll 4
    for (int kt = 0; kt < 12; ++kt) {
        int krow = k0 + kt * 16 + l15;
        int kcl = krow < 0 ? 0 : (krow >= SDIM ? SDIM - 1 : krow);
        const f16x8* kp = (const f16x8*)(Kb + (long)kcl * HD + lg * 8);
        f16x8 kb0 = kp[0], kb1 = kp[4];
        f32x4 acc = {0.f, 0.f, 0.f, 0.f};
        acc = __builtin_amdgcn_mfma_f32_16x16x32_f16(qa0, kb0, acc, 0, 0, 0);
        acc = __builtin_amdgcn_mfma_f32_16x16x32_f16(qa1, kb1, acc, 0, 0, 0);
        int jk = kt * 16 + l15;
        bool kin = (krow >= 0) && (krow < SDIM);
#pragma unroll
        for (int j = 0; j < 4; ++j) {
            int i = iqb + j;
            bool valid = kin && (jk >= i) && (jk <= i + 128);
            float p = valid ? __expf(acc[j] * 0.125f) : 0.f;
            sums[j] += p;
            lsP[(w * 16 + lg * 4 + j) * PSTR + jk] = (_Float16)p;
        }
    }

#pragma unroll
    for (int m = 1; m < 16; m <<= 1) {
#pragma unroll
        for (int j = 0; j < 4; ++j)
            sums[j] += __shfl_xor(sums[j], m, 64);
    }
    float inv[4];
#pragma unroll
    for (int j = 0; j < 4; ++j) inv[j] = 1.f / sums[j];

    __syncthreads();

    f32x4 accy[4] = {};
    const _Float16* prow = &lsP[(w * 16 + l15) * PSTR + lg * 8];
#pragma unroll
    for (int kc = 0; kc < 6; ++kc) {
        f16x8 pa = *(const f16x8*)(prow + kc * 32);
#pragma unroll
        for (int dt = 0; dt < 4; ++dt) {
            f16x8 vb = *(const f16x8*)&lsVT[(dt * 16 + l15) * SSTR + kc * 32 + lg * 8];
            accy[dt] = __builtin_amdgcn_mfma_f32_16x16x32_f16(pa, vb, accy[dt], 0, 0, 0);
        }
    }

    int b = bh / NH, h = bh - (bh / NH) * NH;
    long outbase = ((long)b * SDIM) * HDIM + (long)h * HD;
#pragma unroll
    for (int dt = 0; dt < 4; ++dt) {
#pragma unroll
        for (int j = 0; j < 4; ++j) {
            int srow = q0 + w * 16 + lg * 4 + j;
            yh[outbase + (long)srow * HDIM + dt * 16 + l15] =
                (_Float16)(accy[dt][j] * inv[j]);
        }
    }
}

// ---------------------------------------------------------------------------
extern "C" void kernel_launch(void* const* d_in, const int* in_sizes, int n_in,
                              void* d_out, int out_size, void* d_ws, size_t ws_size,
                              hipStream_t stream)
{
    const float* x    = (const float*)d_in[0];
    const float* cosp = (const float*)d_in[1];
    const float* sinp = (const float*)d_in[2];
    const float* Wqkv = (const float*)d_in[3];
    const float* Wo   = (const float*)d_in[4];
    float* out = (float*)d_out;

    char* ws = (char*)d_ws;
    _Float16* xh    = (_Float16*)(ws);                    // 12,582,912
    _Float16* wqkvh = (_Float16*)(ws + 12582912);         //  3,538,944
    _Float16* woh   = (_Float16*)(ws + 16121856);         //  1,179,648
    _Float16* qh    = (_Float16*)(ws + 17301504);         // 12,582,912
    _Float16* kh    = (_Float16*)(ws + 29884416);         // 12,582,912
    _Float16* vh    = (_Float16*)(ws + 42467328);         // 12,582,912
    _Float16* yh    = (_Float16*)(ws + 55050240);         // 12,582,912 -> 67,633,152 total

    // 1) convert inputs to fp16
    cvt_f32_f16<<<(MROWS * HDIM / 8 + 255) / 256, 256, 0, stream>>>(x, xh, MROWS * HDIM / 8);
    cvt_f32_f16<<<(NQKV * HDIM / 8 + 255) / 256, 256, 0, stream>>>(Wqkv, wqkvh, NQKV * HDIM / 8);
    cvt_f32_f16<<<(HDIM * HDIM / 8 + 255) / 256, 256, 0, stream>>>(Wo, woh, HDIM * HDIM / 8);

    // 2) QKV gemm with fused RoPE + scatter epilogue (128x256, 4-phase)
    {
        dim3 grid((MROWS / 128) * (NQKV / 256));   // 64*9 = 576
        gemm_kernel<4, 1><<<grid, 512, 0, stream>>>(
            xh, wqkvh, nullptr, cosp, sinp, qh, kh, vh, MROWS, NQKV, HDIM);
    }

    // 3) sliding-window MFMA attention
    {
        dim3 grid(BDIM * NH * (SDIM / 64));        // 1536
        attn_mfma<<<grid, 256, 0, stream>>>(qh, kh, vh, yh);
    }

    // 4) output projection (128x128, 4-phase)
    {
        dim3 grid((MROWS / 128) * (HDIM / 128));   // 64*6 = 384
        gemm_kernel<2, 0><<<grid, 256, 0, stream>>>(
            yh, woh, out, nullptr, nullptr, nullptr, nullptr, nullptr,
            MROWS, HDIM, HDIM);
    }
}